// Round 5
// baseline (205.898 us; speedup 1.0000x reference)
//
#include <hip/hip_runtime.h>
#include <hip/hip_bf16.h>
#include <math.h>

static constexpr int kC = 32, kR = 255, kE = 256;

typedef float f32x4 __attribute__((ext_vector_type(4)));
typedef short bf16x8 __attribute__((ext_vector_type(8)));

// Static device scratch (graph-capture-safe). No atomics.
__device__ float g_q0kv[768];            // [512..767] = W_v·cls + b_v
__device__ float g_qw[4 * 256];          // (q0_h^T W_k,h)*scale  [h][e]
__device__ float g_s0[4];                // score of key position 0 per head
__device__ float g_qb[4];                // (q0_h · b_k,h)*scale
__device__ float g_m[256 * 4 * 4];       // chunk max   [bc][chunk][h]
__device__ float g_l[256 * 4 * 4];       // chunk sum   [bc][chunk][h]
__device__ float g_part[256 * 4 * 4 * 256]; // partial xbar [bc][chunk][h][e]

// Row-major bf16 weight caches (direct elementwise casts of the fp32 sources;
// MFMA A-operand wants [OUT][IN] rows — the old transposed e8-major layout is gone).
__device__ unsigned short g_wv_rm[256 * 256];
__device__ unsigned short g_wout_rm[256 * 256];
__device__ unsigned short g_w1_rm[1024 * 256];
__device__ unsigned short g_w2_rm[256 * 1024];

// Activation scratch, bf16, in GLOBAL (L2-resident) to stay under the 64KB
// static-LDS limit. hi/lo split for pre-LN-amplified operands (xbar, ctx).
#define XH_S 1056  // 1024 + 32 pad (breaks 2KB power-of-2 stride)
#define CT_S 264   // 256 + 8 pad
__device__ unsigned short g_xh[256 * XH_S], g_xl[256 * XH_S];
__device__ unsigned short g_ctxh[256 * CT_S], g_ctxl[256 * CT_S];
__device__ unsigned short g_lnsb[256 * CT_S];
__device__ unsigned short g_hsb[256 * XH_S];

__device__ inline unsigned short f2bf(float f) {
  __hip_bfloat16 h = __float2bfloat16(f);
  return __builtin_bit_cast(unsigned short, h);
}
__device__ inline float bf2f(unsigned short u) {
  return __uint_as_float(((unsigned)u) << 16);
}

// ---- Head setup: 4 blocks, one per head. q0/kc rows recomputed in-block. ----
__global__ __launch_bounds__(256) void k_heads(const float* __restrict__ cls,
                                               const float* __restrict__ w_qkv,
                                               const float* __restrict__ b_qkv) {
  const int t = threadIdx.x, wvi = t >> 6, l = t & 63;
  const int h = blockIdx.x;
  __shared__ float q0h[64];
  __shared__ float kch[64];
  {
    const int r = t >> 1, half = t & 1;
    const int row = (r < 64) ? (h * 64 + r) : (256 + h * 64 + (r - 64));
    const float4* wp = (const float4*)(w_qkv + (size_t)row * 256 + half * 128);
    const float4* cp = (const float4*)cls + half * 32;
    float a = 0.f;
#pragma unroll 8
    for (int j = 0; j < 32; ++j) {
      float4 w4 = wp[j];
      float4 cv = cp[j];
      a += w4.x * cv.x + w4.y * cv.y + w4.z * cv.z + w4.w * cv.w;
    }
    a += __shfl_xor(a, 1);
    if (half == 0) {
      const float val = a + b_qkv[row];
      if (r < 64) q0h[r] = val; else kch[r - 64] = val;
    }
  }
  __syncthreads();

  float acc = 0.f;
#pragma unroll 8
  for (int j = 0; j < 64; ++j)
    acc += q0h[j] * w_qkv[(size_t)(256 + h * 64 + j) * 256 + t];
  g_qw[h * 256 + t] = acc * 0.125f;
  if (wvi == 0) {
    const float q = q0h[l];
    float pk = q * kch[l];                    // kc includes b_k
    float pb = q * b_qkv[256 + h * 64 + l];
#pragma unroll
    for (int m = 1; m < 64; m <<= 1) {
      pk += __shfl_xor(pk, m);
      pb += __shfl_xor(pb, m);
    }
    if (l == 0) {
      g_s0[h] = pk * 0.125f;
      g_qb[h] = pb * 0.125f;
    }
  }
}

// ---- Attention chunks + rider blocks.
//   blocks 0..1023    : scores + chunk softmax + partial weighted sums (proven)
//   blocks 1024..1063 : straight row-major fp32->bf16 weight casts (16384 el each)
//   blocks 1064..1127 : v rows of W_qkv·cls + b (wave-per-row 1KB dot) ----
__global__ __launch_bounds__(256) void k_attn(const float* __restrict__ x,
                                              const int* __restrict__ real_cols,
                                              const int* __restrict__ real_rows,
                                              const float* __restrict__ cls,
                                              const float* __restrict__ w_qkv,
                                              const float* __restrict__ b_qkv,
                                              const float* __restrict__ w_out,
                                              const float* __restrict__ w1,
                                              const float* __restrict__ w2) {
  const int t = threadIdx.x, wv = t >> 6, l = t & 63;
  const int bid = blockIdx.x;
  __shared__ __align__(16) char smem[71680];

  if (bid >= 1064) {  // ---- v rows 512..767: wave-per-row dot ----
    const int row = 512 + (bid - 1064) * 4 + wv;
    float4 w4 = *((const float4*)(w_qkv + (size_t)row * 256) + l);
    float4 c4 = *((const float4*)cls + l);
    float a = w4.x * c4.x + w4.y * c4.y + w4.z * c4.z + w4.w * c4.w;
#pragma unroll
    for (int m = 1; m < 64; m <<= 1) a += __shfl_xor(a, m);
    if (l == 0) g_q0kv[row] = a + b_qkv[row];
    return;
  }

  if (bid >= 1024) {  // ---- row-major casts: 16384 elements per block ----
    const int u = bid - 1024;  // 0..39
    const float* src;
    unsigned short* dst;
    if (u < 4) { src = w_qkv + 512 * 256 + u * 16384; dst = g_wv_rm + u * 16384; }
    else if (u < 8) { src = w_out + (u - 4) * 16384; dst = g_wout_rm + (u - 4) * 16384; }
    else if (u < 24) { src = w1 + (u - 8) * 16384; dst = g_w1_rm + (u - 8) * 16384; }
    else { src = w2 + (u - 24) * 16384; dst = g_w2_rm + (u - 24) * 16384; }
    const float4* s4 = (const float4*)src;
    ushort4* d4 = (ushort4*)dst;
#pragma unroll 4
    for (int i = 0; i < 16; ++i) {
      float4 v = s4[i * 256 + t];
      ushort4 o;
      o.x = f2bf(v.x); o.y = f2bf(v.y); o.z = f2bf(v.z); o.w = f2bf(v.w);
      d4[i * 256 + t] = o;
    }
    return;
  }

  // ---- attention chunk blocks (proven 64-row version) ----
  const int bc = bid >> 2, chunk = bid & 3;
  const int b = bc >> 5, c = bc & 31;
  if (c >= real_cols[b]) return;
  const int rr = real_rows[b];
  const int r0 = chunk * 64;
  const int nr = min(64, rr - r0);
  if (nr <= 0) return;

  float (*xs)[260] = (float(*)[260])smem;                    // 66560 B
  float (*qws)[256] = (float(*)[256])(smem + 66560);         //  4096 B
  float (*ps)[64] = (float(*)[64])(smem + 70656);            //  1024 B

#pragma unroll
  for (int i = 0; i < 4; ++i) qws[i][t] = g_qw[i * 256 + t];

  const float* xb = x + ((size_t)bc * kR + r0) * kE;
  for (int r = wv; r < nr; r += 4)
    *(float4*)&xs[r][4 * l] = *(const float4*)(xb + (size_t)r * kE + 4 * l);
  __syncthreads();

  const int h = wv, row = l;
  float acc = 0.f;
  const float4* qrow = (const float4*)&qws[h][0];
  const float4* xrow = (const float4*)&xs[row][0];
#pragma unroll 8
  for (int e4 = 0; e4 < 64; ++e4) {
    float4 q4 = qrow[e4];
    float4 x4 = xrow[e4];
    acc += q4.x * x4.x + q4.y * x4.y + q4.z * x4.z + q4.w * x4.w;
  }
  float s = (row < nr) ? acc + g_qb[h] : -1e30f;
  float mx = s;
#pragma unroll
  for (int m = 1; m < 64; m <<= 1) mx = fmaxf(mx, __shfl_xor(mx, m));
  float p = (row < nr) ? __expf(s - mx) : 0.f;
  float lsum = p;
#pragma unroll
  for (int m = 1; m < 64; m <<= 1) lsum += __shfl_xor(lsum, m);
  ps[h][row] = p;
  if (l == 0) {
    g_m[(bc * 4 + chunk) * 4 + h] = mx;
    g_l[(bc * 4 + chunk) * 4 + h] = lsum;
  }
  __syncthreads();

  float a0 = 0.f, a1 = 0.f, a2 = 0.f, a3 = 0.f;
  for (int r2 = 0; r2 < nr; ++r2) {
    float xv = xs[r2][t];
    a0 += ps[0][r2] * xv;
    a1 += ps[1][r2] * xv;
    a2 += ps[2][r2] * xv;
    a3 += ps[3][r2] * xv;
  }
  float* pp = g_part + (size_t)(bc * 4 + chunk) * 4 * 256;
  pp[0 * 256 + t] = a0;
  pp[1 * 256 + t] = a1;
  pp[2 * 256 + t] = a2;
  pp[3 * 256 + t] = a3;
}

// ---- MFMA tail: 16 blocks x 1024 threads; 16 tokens/block (one column-group
//      half, so real_cols/real_rows are block-uniform). Phases:
//      merge -> xbar(hi/lo bf16) -> CTX mfma -> MHA mfma -> LN -> FFN1 mfma ->
//      FFN2 mfma + residual + mask. Replaces the GEMV k_token (round-4 lesson:
//      throughput-bound on per-thread FMA+unpack+uniform-ds_read work; MFMA
//      cuts instructions ~8x and removes the DS-pipe inner loop entirely). ----
__global__ __launch_bounds__(1024) void k_tail_mm(const int* __restrict__ real_cols,
                                                  const int* __restrict__ real_rows,
                                                  const float* __restrict__ b_qkv,
                                                  const float* __restrict__ b_out,
                                                  const float* __restrict__ ln_g,
                                                  const float* __restrict__ ln_b,
                                                  const float* __restrict__ b1,
                                                  const float* __restrict__ b2,
                                                  float* __restrict__ out) {
  const int tg = blockIdx.x;           // token group: bc = tg*16 .. tg*16+15
  const int t = threadIdx.x, wv = t >> 6, l = t & 63;
  const int bidx = tg >> 1;            // batch index (16 tokens = half a col-group)
  const int ncols = real_cols[bidx];
  if ((tg & 1) * 16 >= ncols) {        // whole block masked: zero-fill, leave
    float4 z = {0.f, 0.f, 0.f, 0.f};
    ((float4*)out)[(size_t)(tg * 16 + (t >> 6)) * 64 + (t & 63)] = z;
    return;
  }
  const int nch = (real_rows[bidx] + 63) >> 6;

  __shared__ float s_mh[16 * 257];     // mha pre-LN (fp32)
  __shared__ float s_lnf[16 * 260];    // LN output fp32 (exact residual)
  __shared__ float s_al[16][4][4];
  __shared__ float s_p0[16][4];
  __shared__ float s_redS[16], s_redQ[16];

  // -- Phase 0: flash-merge coefficients, (tok, h) on threads 0..63 --
  if (t < 64) {
    const int tok = t >> 2, h = t & 3;
    const int bc = tg * 16 + tok;
    const float s0 = g_s0[h];
    float M = s0;
    for (int ch = 0; ch < nch; ++ch) M = fmaxf(M, g_m[(bc * 4 + ch) * 4 + h]);
    float lt = __expf(s0 - M);
    const float w0 = lt;
    float av[4] = {0.f, 0.f, 0.f, 0.f};
    for (int ch = 0; ch < nch; ++ch) {
      float e = __expf(g_m[(bc * 4 + ch) * 4 + h] - M);
      av[ch] = e;
      lt += g_l[(bc * 4 + ch) * 4 + h] * e;
    }
    const float inv = 1.f / lt;
#pragma unroll
    for (int ch = 0; ch < 4; ++ch) s_al[tok][h][ch] = av[ch] * inv;
    s_p0[tok][h] = w0 * inv;
  }
  __syncthreads();

  // -- Phase 1: xbar merge -> hi/lo bf16 in global scratch --
  {
    const int tok = t >> 6, j = t & 63;
    const int bc = tg * 16 + tok;
#pragma unroll
    for (int h = 0; h < 4; ++h) {
      float4 a = {0.f, 0.f, 0.f, 0.f};
      for (int ch = 0; ch < nch; ++ch) {
        const float al = s_al[tok][h][ch];
        const float4 p = *(const float4*)(g_part + (size_t)(bc * 4 + ch) * 1024 + h * 256 + j * 4);
        a.x += al * p.x; a.y += al * p.y; a.z += al * p.z; a.w += al * p.w;
      }
      ushort4 hi, lo;
      hi.x = f2bf(a.x); lo.x = f2bf(a.x - bf2f(hi.x));
      hi.y = f2bf(a.y); lo.y = f2bf(a.y - bf2f(hi.y));
      hi.z = f2bf(a.z); lo.z = f2bf(a.z - bf2f(hi.z));
      hi.w = f2bf(a.w); lo.w = f2bf(a.w - bf2f(hi.w));
      *(ushort4*)(g_xh + (size_t)bc * XH_S + h * 256 + j * 4) = hi;
      *(ushort4*)(g_xl + (size_t)bc * XH_S + h * 256 + j * 4) = lo;
    }
  }
  __syncthreads();

  const int r = l & 15, q = l >> 4;    // MFMA lane coords (16-row / k-quadrant)
  const int bcr = tg * 16 + r;         // token row for B operands / epilogues

  // -- Phase 2: CTX = blockdiag W_v GEMM; wave -> (head h, 16-f tile) --
  {
    const int h = wv >> 2, f0 = h * 64 + (wv & 3) * 16;
    const unsigned short* wa = g_wv_rm + (size_t)(f0 + r) * 256 + 8 * q;
    const unsigned short* xh = g_xh + (size_t)bcr * XH_S + h * 256 + 8 * q;
    const unsigned short* xl = g_xl + (size_t)bcr * XH_S + h * 256 + 8 * q;
    f32x4 acc = {0.f, 0.f, 0.f, 0.f};
#pragma unroll
    for (int ks = 0; ks < 8; ++ks) {
      bf16x8 a = *(const bf16x8*)(wa + ks * 32);
      acc = __builtin_amdgcn_mfma_f32_16x16x32_bf16(a, *(const bf16x8*)(xh + ks * 32), acc, 0, 0, 0);
      acc = __builtin_amdgcn_mfma_f32_16x16x32_bf16(a, *(const bf16x8*)(xl + ks * 32), acc, 0, 0, 0);
    }
    const float p0 = s_p0[r][h];
#pragma unroll
    for (int i = 0; i < 4; ++i) {
      const int f = f0 + q * 4 + i;
      const float v = acc[i] + p0 * g_q0kv[512 + f] + (1.f - p0) * b_qkv[512 + f];
      const unsigned short hu = f2bf(v);
      g_ctxh[(size_t)bcr * CT_S + f] = hu;
      g_ctxl[(size_t)bcr * CT_S + f] = f2bf(v - bf2f(hu));
    }
  }
  __syncthreads();

  // -- Phase 3: MHA = CTX @ W_out^T; wave -> 16-g tile --
  {
    const int g0 = wv * 16;
    const unsigned short* wa = g_wout_rm + (size_t)(g0 + r) * 256 + 8 * q;
    const unsigned short* ch_ = g_ctxh + (size_t)bcr * CT_S + 8 * q;
    const unsigned short* cl_ = g_ctxl + (size_t)bcr * CT_S + 8 * q;
    f32x4 acc = {0.f, 0.f, 0.f, 0.f};
#pragma unroll
    for (int ks = 0; ks < 8; ++ks) {
      bf16x8 a = *(const bf16x8*)(wa + ks * 32);
      acc = __builtin_amdgcn_mfma_f32_16x16x32_bf16(a, *(const bf16x8*)(ch_ + ks * 32), acc, 0, 0, 0);
      acc = __builtin_amdgcn_mfma_f32_16x16x32_bf16(a, *(const bf16x8*)(cl_ + ks * 32), acc, 0, 0, 0);
    }
#pragma unroll
    for (int i = 0; i < 4; ++i) {
      const int g = g0 + q * 4 + i;
      s_mh[r * 257 + g] = acc[i] + b_out[g];  // tok = r (D col), row = g
    }
  }
  __syncthreads();

  // -- Phase 4a: LN stats (per-token sums; 16 segs of a token live in one wave) --
  if (t < 256) {
    const int tok = t >> 4, seg = t & 15;
    float s1 = 0.f, s2 = 0.f;
#pragma unroll
    for (int i = 0; i < 16; ++i) {
      const float v = s_mh[tok * 257 + seg * 16 + i];
      s1 += v; s2 += v * v;
    }
#pragma unroll
    for (int m = 1; m < 16; m <<= 1) {
      s1 += __shfl_xor(s1, m);
      s2 += __shfl_xor(s2, m);
    }
    if (seg == 0) { s_redS[tok] = s1; s_redQ[tok] = s2; }
  }
  __syncthreads();

  // -- Phase 4b: LN apply -> lnf (fp32, residual) + lns bf16 scratch --
  {
    const int tok = t >> 6, e4 = t & 63;
    const float mu = s_redS[tok] * (1.f / 256.f);
    const float var = s_redQ[tok] * (1.f / 256.f) - mu * mu;
    const float rs = rsqrtf(var + 1e-5f);
    const float4 gg = *((const float4*)ln_g + e4);
    const float4 bb = *((const float4*)ln_b + e4);
    float4 o;
    o.x = (s_mh[tok * 257 + e4 * 4 + 0] - mu) * rs * gg.x + bb.x;
    o.y = (s_mh[tok * 257 + e4 * 4 + 1] - mu) * rs * gg.y + bb.y;
    o.z = (s_mh[tok * 257 + e4 * 4 + 2] - mu) * rs * gg.z + bb.z;
    o.w = (s_mh[tok * 257 + e4 * 4 + 3] - mu) * rs * gg.w + bb.w;
    *(float4*)&s_lnf[tok * 260 + e4 * 4] = o;
    ushort4 ob;
    ob.x = f2bf(o.x); ob.y = f2bf(o.y); ob.z = f2bf(o.z); ob.w = f2bf(o.w);
    *(ushort4*)(g_lnsb + (size_t)(tg * 16 + tok) * CT_S + e4 * 4) = ob;
  }
  __syncthreads();

  // -- Phase 5: FFN1 = relu(LN @ W1^T); wave -> 4 16-f tiles (64 f-range) --
  {
    const unsigned short* lb = g_lnsb + (size_t)bcr * CT_S + 8 * q;
#pragma unroll
    for (int mt = 0; mt < 4; ++mt) {
      const int f0 = wv * 64 + mt * 16;
      const unsigned short* wa = g_w1_rm + (size_t)(f0 + r) * 256 + 8 * q;
      f32x4 acc = {0.f, 0.f, 0.f, 0.f};
#pragma unroll
      for (int ks = 0; ks < 8; ++ks) {
        acc = __builtin_amdgcn_mfma_f32_16x16x32_bf16(
            *(const bf16x8*)(wa + ks * 32), *(const bf16x8*)(lb + ks * 32), acc, 0, 0, 0);
      }
#pragma unroll
      for (int i = 0; i < 4; ++i) {
        const int f = f0 + q * 4 + i;
        g_hsb[(size_t)bcr * XH_S + f] = f2bf(fmaxf(acc[i] + b1[f], 0.f));
      }
    }
  }
  __syncthreads();

  // -- Phase 6: FFN2 + residual + mask; wave -> 16-e tile, K=1024 --
  {
    const int e0 = wv * 16;
    const unsigned short* wa = g_w2_rm + (size_t)(e0 + r) * 1024 + 8 * q;
    const unsigned short* hb = g_hsb + (size_t)bcr * XH_S + 8 * q;
    f32x4 acc = {0.f, 0.f, 0.f, 0.f};
#pragma unroll 8
    for (int ks = 0; ks < 32; ++ks) {
      acc = __builtin_amdgcn_mfma_f32_16x16x32_bf16(
          *(const bf16x8*)(wa + ks * 32), *(const bf16x8*)(hb + ks * 32), acc, 0, 0, 0);
    }
    const bool valid = ((tg & 1) * 16 + r) < ncols;
#pragma unroll
    for (int i = 0; i < 4; ++i) {
      const int e = e0 + q * 4 + i;
      const float v = s_lnf[r * 260 + e] + acc[i] + b2[e];
      out[(size_t)bcr * 256 + e] = valid ? v : 0.f;
    }
  }
}

extern "C" void kernel_launch(void* const* d_in, const int* in_sizes, int n_in,
                              void* d_out, int out_size, void* d_ws, size_t ws_size,
                              hipStream_t stream) {
  const float* x = (const float*)d_in[0];
  const int* real_cols = (const int*)d_in[1];
  const int* real_rows = (const int*)d_in[2];
  const float* cls = (const float*)d_in[3];
  const float* w_qkv = (const float*)d_in[4];
  const float* b_qkv = (const float*)d_in[5];
  const float* w_out = (const float*)d_in[6];
  const float* b_out = (const float*)d_in[7];
  const float* ln_g = (const float*)d_in[8];
  const float* ln_b = (const float*)d_in[9];
  const float* w1 = (const float*)d_in[10];
  const float* b1 = (const float*)d_in[11];
  const float* w2 = (const float*)d_in[12];
  const float* b2 = (const float*)d_in[13];
  float* out = (float*)d_out;
  (void)in_sizes; (void)n_in; (void)out_size; (void)d_ws; (void)ws_size;

  k_heads<<<4, 256, 0, stream>>>(cls, w_qkv, b_qkv);
  k_attn<<<1128, 256, 0, stream>>>(x, real_cols, real_rows, cls, w_qkv, b_qkv, w_out, w1, w2);
  k_tail_mm<<<16, 1024, 0, stream>>>(real_cols, real_rows, b_qkv, b_out, ln_g, ln_b, b1, b2, out);
}

// Round 6
// 176.860 us; speedup vs baseline: 1.1642x; 1.1642x over previous
//
#include <hip/hip_runtime.h>
#include <hip/hip_bf16.h>
#include <math.h>

static constexpr int kC = 32, kR = 255, kE = 256;

// Static device scratch (graph-capture-safe). No atomics.
__device__ float g_q0kv[768];            // [512..767] = W_v·cls + b_v
__device__ float g_qw[4 * 256];          // (q0_h^T W_k,h)*scale  [h][e]
__device__ float g_s0[4];                // score of key position 0 per head
__device__ float g_qb[4];                // (q0_h · b_k,h)*scale
__device__ float g_m[256 * 4 * 4];       // chunk max   [bc][chunk][h]
__device__ float g_l[256 * 4 * 4];       // chunk sum   [bc][chunk][h]
__device__ float g_part[256 * 4 * 4 * 256]; // partial xbar [bc][chunk][h][e]

// Per-token fp32 activation scratch. Round-5 lesson: global-scratch RW across
// __syncthreads within a block is correct on gfx950 (vmcnt(0) drain + L1
// write-through). All reads of these in k_token are WAVE-UNIFORM -> single
// broadcast VMEM transaction, freeing the DS pipe (round-2 k_token's limiter).
__device__ float g_xbar[256 * 1024];
__device__ float g_ctx[256 * 256];
__device__ float g_lnsf[256 * 256];
__device__ float g_hactf[256 * 1024];

// bf16 weight caches, e8-major transposed: index ((e>>3)*OUT + o)*8 + (e&7).
// Consumers load uint4 at (e8*OUT+t)*16B -> lane-consecutive (round-6 lesson).
__device__ unsigned short g_wv_bf[256 * 256];    // OUT=256, IN=256
__device__ unsigned short g_wout_bf[256 * 256];  // OUT=256, IN=256
__device__ unsigned short g_w1_bf[1024 * 256];   // OUT=1024, IN=256
__device__ unsigned short g_w2_bf[256 * 1024];   // OUT=256, IN=1024

__device__ inline unsigned short f2bf(float f) {
  __hip_bfloat16 h = __float2bfloat16(f);
  return __builtin_bit_cast(unsigned short, h);
}
__device__ inline float bflo(unsigned int u) { return __uint_as_float(u << 16); }
__device__ inline float bfhi(unsigned int u) { return __uint_as_float(u & 0xffff0000u); }

// ---- Head setup: 4 blocks, one per head. q0/kc rows recomputed in-block. ----
__global__ __launch_bounds__(256) void k_heads(const float* __restrict__ cls,
                                               const float* __restrict__ w_qkv,
                                               const float* __restrict__ b_qkv) {
  const int t = threadIdx.x, wvi = t >> 6, l = t & 63;
  const int h = blockIdx.x;
  __shared__ float q0h[64];
  __shared__ float kch[64];
  {
    const int r = t >> 1, half = t & 1;
    const int row = (r < 64) ? (h * 64 + r) : (256 + h * 64 + (r - 64));
    const float4* wp = (const float4*)(w_qkv + (size_t)row * 256 + half * 128);
    const float4* cp = (const float4*)cls + half * 32;
    float a = 0.f;
#pragma unroll 8
    for (int j = 0; j < 32; ++j) {
      float4 w4 = wp[j];
      float4 cv = cp[j];
      a += w4.x * cv.x + w4.y * cv.y + w4.z * cv.z + w4.w * cv.w;
    }
    a += __shfl_xor(a, 1);
    if (half == 0) {
      const float val = a + b_qkv[row];
      if (r < 64) q0h[r] = val; else kch[r - 64] = val;
    }
  }
  __syncthreads();

  float acc = 0.f;
#pragma unroll 8
  for (int j = 0; j < 64; ++j)
    acc += q0h[j] * w_qkv[(size_t)(256 + h * 64 + j) * 256 + t];
  g_qw[h * 256 + t] = acc * 0.125f;
  if (wvi == 0) {
    const float q = q0h[l];
    float pk = q * kch[l];                    // kc includes b_k
    float pb = q * b_qkv[256 + h * 64 + l];
#pragma unroll
    for (int m = 1; m < 64; m <<= 1) {
      pk += __shfl_xor(pk, m);
      pb += __shfl_xor(pb, m);
    }
    if (l == 0) {
      g_s0[h] = pk * 0.125f;
      g_qb[h] = pb * 0.125f;
    }
  }
}

// ---- Attention chunks + rider blocks (round-2 proven config: 64-row chunks).
//   blocks 0..1023    : scores + chunk softmax + partial weighted sums
//   blocks 1024..1063 : LDS-tiled transposing bf16 casts (feed k_token only)
//   blocks 1064..1127 : v rows of W_qkv·cls + b (wave-per-row 1KB dot) ----
__global__ __launch_bounds__(256) void k_attn(const float* __restrict__ x,
                                              const int* __restrict__ real_cols,
                                              const int* __restrict__ real_rows,
                                              const float* __restrict__ cls,
                                              const float* __restrict__ w_qkv,
                                              const float* __restrict__ b_qkv,
                                              const float* __restrict__ w_out,
                                              const float* __restrict__ w1,
                                              const float* __restrict__ w2) {
  const int t = threadIdx.x, wv = t >> 6, l = t & 63;
  const int bid = blockIdx.x;
  __shared__ __align__(16) char smem[71680];

  if (bid >= 1064) {  // ---- v rows 512..767: wave-per-row dot ----
    const int row = 512 + (bid - 1064) * 4 + wv;
    float4 w4 = *((const float4*)(w_qkv + (size_t)row * 256) + l);
    float4 c4 = *((const float4*)cls + l);
    float a = w4.x * c4.x + w4.y * c4.y + w4.z * c4.z + w4.w * c4.w;
#pragma unroll
    for (int m = 1; m < 64; m <<= 1) a += __shfl_xor(a, m);
    if (l == 0) g_q0kv[row] = a + b_qkv[row];
    return;
  }

  if (bid >= 1024) {  // ---- cast tiles: 64 out-rows x 256 in-cols ----
    const int u = bid - 1024;  // 0..39
    const float* src;
    unsigned short* dst;
    int R, C, o0, e0;
    if (u < 4) { src = w_qkv + 512 * 256; dst = g_wv_bf; R = 256; C = 256; o0 = u * 64; e0 = 0; }
    else if (u < 8) { src = w_out; dst = g_wout_bf; R = 256; C = 256; o0 = (u - 4) * 64; e0 = 0; }
    else if (u < 24) { src = w1; dst = g_w1_bf; R = 1024; C = 256; o0 = (u - 8) * 64; e0 = 0; }
    else { const int v = u - 24; src = w2; dst = g_w2_bf; R = 256; C = 1024; o0 = (v >> 2) * 64; e0 = (v & 3) * 256; }

    unsigned short* tile = (unsigned short*)smem;  // 64*260 ushort = 33280 B
    for (int r = wv; r < 64; r += 4) {
      float4 v = *((const float4*)(src + (size_t)(o0 + r) * C + e0) + l);
      ushort4 ov;
      ov.x = f2bf(v.x); ov.y = f2bf(v.y); ov.z = f2bf(v.z); ov.w = f2bf(v.w);
      *(ushort4*)&tile[r * 260 + 4 * l] = ov;
    }
    __syncthreads();
    const int e80 = e0 >> 3;
    for (int e8l = wv; e8l < 32; e8l += 4) {
      const unsigned int* tp = (const unsigned int*)&tile[l * 260 + e8l * 8];
      uint4 o;
      o.x = tp[0]; o.y = tp[1]; o.z = tp[2]; o.w = tp[3];
      *(uint4*)(dst + ((size_t)(e80 + e8l) * R + o0 + l) * 8) = o;
    }
    return;
  }

  // ---- attention chunk blocks (proven 64-row version) ----
  const int bc = bid >> 2, chunk = bid & 3;
  const int b = bc >> 5, c = bc & 31;
  if (c >= real_cols[b]) return;
  const int rr = real_rows[b];
  const int r0 = chunk * 64;
  const int nr = min(64, rr - r0);
  if (nr <= 0) return;

  float (*xs)[260] = (float(*)[260])smem;                    // 66560 B
  float (*qws)[256] = (float(*)[256])(smem + 66560);         //  4096 B
  float (*ps)[64] = (float(*)[64])(smem + 70656);            //  1024 B

#pragma unroll
  for (int i = 0; i < 4; ++i) qws[i][t] = g_qw[i * 256 + t];

  const float* xb = x + ((size_t)bc * kR + r0) * kE;
  for (int r = wv; r < nr; r += 4)
    *(float4*)&xs[r][4 * l] = *(const float4*)(xb + (size_t)r * kE + 4 * l);
  __syncthreads();

  const int h = wv, row = l;
  float acc = 0.f;
  const float4* qrow = (const float4*)&qws[h][0];
  const float4* xrow = (const float4*)&xs[row][0];
#pragma unroll 8
  for (int e4 = 0; e4 < 64; ++e4) {
    float4 q4 = qrow[e4];
    float4 x4 = xrow[e4];
    acc += q4.x * x4.x + q4.y * x4.y + q4.z * x4.z + q4.w * x4.w;
  }
  float s = (row < nr) ? acc + g_qb[h] : -1e30f;
  float mx = s;
#pragma unroll
  for (int m = 1; m < 64; m <<= 1) mx = fmaxf(mx, __shfl_xor(mx, m));
  float p = (row < nr) ? __expf(s - mx) : 0.f;
  float lsum = p;
#pragma unroll
  for (int m = 1; m < 64; m <<= 1) lsum += __shfl_xor(lsum, m);
  ps[h][row] = p;
  if (l == 0) {
    g_m[(bc * 4 + chunk) * 4 + h] = mx;
    g_l[(bc * 4 + chunk) * 4 + h] = lsum;
  }
  __syncthreads();

  float a0 = 0.f, a1 = 0.f, a2 = 0.f, a3 = 0.f;
  for (int r2 = 0; r2 < nr; ++r2) {
    float xv = xs[r2][t];
    a0 += ps[0][r2] * xv;
    a1 += ps[1][r2] * xv;
    a2 += ps[2][r2] * xv;
    a3 += ps[3][r2] * xv;
  }
  float* pp = g_part + (size_t)(bc * 4 + chunk) * 4 * 256;
  pp[0 * 256 + t] = a0;
  pp[1 * 256 + t] = a1;
  pp[2 * 256 + t] = a2;
  pp[3 * 256 + t] = a3;
}

// ---- Fused per-token tail, WIDE (round-2 structure) with DS-pipe removal:
//      activations live in global scratch and are read with WAVE-UNIFORM
//      addresses (1 broadcast VMEM transaction, L1-hot) instead of ds_read.
//      LDS keeps only the 4KB split-K reduction buffers. (Round-5 lesson:
//      global RW across __syncthreads is correct; round-2 lesson: k_token was
//      DS-pipe-bound at ~160 ds_read_b128/thread.) ----
__global__ __launch_bounds__(1024) void k_token(const int* __restrict__ real_cols,
                                                const int* __restrict__ real_rows,
                                                const float* __restrict__ b_qkv,
                                                const float* __restrict__ b_out,
                                                const float* __restrict__ ln_g,
                                                const float* __restrict__ ln_b,
                                                const float* __restrict__ b1,
                                                const float* __restrict__ b2,
                                                float* __restrict__ out) {
  const int bc = blockIdx.x, b = bc >> 5, c = bc & 31;
  const int t = threadIdx.x, wv = t >> 6, l = t & 63;
  if (c >= real_cols[b]) {  // masked column: write the zero mask and leave
    if (t < 256) out[(size_t)bc * 256 + t] = 0.f;
    return;
  }
  const int rr = real_rows[b];
  const int nch = (rr + 63) >> 6;

  __shared__ float part[4][256];  // split-K partials (reused per phase)
  __shared__ float al[4][4];
  __shared__ float p0s[4];
  __shared__ float rb[2][4];

  if (t < 4) {  // flash-merge chunk stats, head h = t
    const int h = t;
    const float s0 = g_s0[h];
    float M = s0;
    for (int ch = 0; ch < nch; ++ch) M = fmaxf(M, g_m[(bc * 4 + ch) * 4 + h]);
    float lt = __expf(s0 - M);
    const float w0 = lt;
    float av[4] = {0.f, 0.f, 0.f, 0.f};
    for (int ch = 0; ch < nch; ++ch) {
      float e = __expf(g_m[(bc * 4 + ch) * 4 + h] - M);
      av[ch] = e;
      lt += g_l[(bc * 4 + ch) * 4 + h] * e;
    }
    const float inv = 1.f / lt;
#pragma unroll
    for (int ch = 0; ch < 4; ++ch) al[h][ch] = av[ch] * inv;
    p0s[h] = w0 * inv;
  }
  __syncthreads();

  {  // xbar merge -> global: thread t -> (h = t>>8, e = t&255); coalesced
    const int h = t >> 8, e = t & 255;
    float a = 0.f;
    for (int ch = 0; ch < nch; ++ch)
      a += al[h][ch] * g_part[(size_t)(bc * 4 + ch) * 1024 + h * 256 + e];
    g_xbar[(size_t)bc * 1024 + h * 256 + e] = a;
  }
  __syncthreads();

  {  // ctx: f = t&255, split-K group q = t>>8; acts via uniform VMEM
    const int f = t & 255, q = t >> 8, h = f >> 6;  // h wave-uniform
    const uint4* wr = (const uint4*)g_wv_bf;
    const float4* v4p = (const float4*)(g_xbar + (size_t)bc * 1024 + h * 256);
    float acc = 0.f;
#pragma unroll
    for (int i = 0; i < 8; ++i) {
      const int e8 = q * 8 + i;
      uint4 w = wr[e8 * 256 + f];
      float4 a = v4p[2 * e8], bb = v4p[2 * e8 + 1];
      acc += bflo(w.x) * a.x + bfhi(w.x) * a.y + bflo(w.y) * a.z + bfhi(w.y) * a.w +
             bflo(w.z) * bb.x + bfhi(w.z) * bb.y + bflo(w.w) * bb.z + bfhi(w.w) * bb.w;
    }
    part[q][f] = acc;
  }
  __syncthreads();
  if (t < 256) {
    const int h = t >> 6;
    const float p0 = p0s[h];
    g_ctx[(size_t)bc * 256 + t] = part[0][t] + part[1][t] + part[2][t] + part[3][t] +
                                  p0 * g_q0kv[512 + t] + (1.f - p0) * b_qkv[512 + t];
  }
  __syncthreads();

  {  // mha: g = t&255, split-K-4 over e8; acts via uniform VMEM
    const int g = t & 255, q = t >> 8;
    const uint4* wr = (const uint4*)g_wout_bf;
    const float4* c4 = (const float4*)(g_ctx + (size_t)bc * 256);
    float acc = 0.f;
#pragma unroll
    for (int i = 0; i < 8; ++i) {
      const int e8 = q * 8 + i;
      uint4 w = wr[e8 * 256 + g];
      float4 a = c4[2 * e8], bb = c4[2 * e8 + 1];
      acc += bflo(w.x) * a.x + bfhi(w.x) * a.y + bflo(w.y) * a.z + bfhi(w.y) * a.w +
             bflo(w.z) * bb.x + bfhi(w.z) * bb.y + bflo(w.w) * bb.z + bfhi(w.w) * bb.w;
    }
    part[q][g] = acc;
  }
  __syncthreads();

  float mh = 0.f;
  if (t < 256)
    mh = part[0][t] + part[1][t] + part[2][t] + part[3][t] + b_out[t];
  {  // LN stats: shuffles run on all threads (garbage above t<256, unused)
    float s1 = mh, s2 = mh * mh;
#pragma unroll
    for (int m = 1; m < 64; m <<= 1) {
      s1 += __shfl_xor(s1, m);
      s2 += __shfl_xor(s2, m);
    }
    if (t < 256 && l == 0) {
      rb[0][wv] = s1;
      rb[1][wv] = s2;
    }
  }
  __syncthreads();
  if (t < 256) {
    const float mu = (rb[0][0] + rb[0][1] + rb[0][2] + rb[0][3]) * (1.f / 256.f);
    const float msq = (rb[1][0] + rb[1][1] + rb[1][2] + rb[1][3]) * (1.f / 256.f);
    const float var = msq - mu * mu;
    g_lnsf[(size_t)bc * 256 + t] = (mh - mu) * rsqrtf(var + 1e-5f) * ln_g[t] + ln_b[t];
  }
  __syncthreads();

  {  // FFN1: thread t computes f = t; acts via uniform VMEM; coalesced write
    const uint4* wr = (const uint4*)g_w1_bf;
    const float4* lp = (const float4*)(g_lnsf + (size_t)bc * 256);
    float acc = b1[t];
#pragma unroll 8
    for (int e8 = 0; e8 < 32; ++e8) {
      uint4 w = wr[e8 * 1024 + t];
      const float4 a = lp[2 * e8];
      const float4 bbv = lp[2 * e8 + 1];
      acc += bflo(w.x) * a.x + bfhi(w.x) * a.y + bflo(w.y) * a.z + bfhi(w.y) * a.w +
             bflo(w.z) * bbv.x + bfhi(w.z) * bbv.y + bflo(w.w) * bbv.z + bfhi(w.w) * bbv.w;
    }
    g_hactf[(size_t)bc * 1024 + t] = fmaxf(acc, 0.f);
  }
  __syncthreads();

  {  // FFN2: e = t&255, split-K group q = t>>8 over f8; acts uniform VMEM
    const int e = t & 255, q = t >> 8;
    const uint4* wr = (const uint4*)g_w2_bf;
    const float4* h4 = (const float4*)(g_hactf + (size_t)bc * 1024);
    float acc = 0.f;
#pragma unroll 8
    for (int i = 0; i < 32; ++i) {
      const int f8 = q * 32 + i;
      uint4 w = wr[f8 * 256 + e];
      float4 a = h4[2 * f8], bb = h4[2 * f8 + 1];
      acc += bflo(w.x) * a.x + bfhi(w.x) * a.y + bflo(w.y) * a.z + bfhi(w.y) * a.w +
             bflo(w.z) * bb.x + bfhi(w.z) * bb.y + bflo(w.w) * bb.z + bfhi(w.w) * bb.w;
    }
    part[q][e] = acc;
  }
  __syncthreads();
  if (t < 256)
    out[(size_t)bc * 256 + t] = g_lnsf[(size_t)bc * 256 + t] +
                                part[0][t] + part[1][t] + part[2][t] + part[3][t] + b2[t];
}

extern "C" void kernel_launch(void* const* d_in, const int* in_sizes, int n_in,
                              void* d_out, int out_size, void* d_ws, size_t ws_size,
                              hipStream_t stream) {
  const float* x = (const float*)d_in[0];
  const int* real_cols = (const int*)d_in[1];
  const int* real_rows = (const int*)d_in[2];
  const float* cls = (const float*)d_in[3];
  const float* w_qkv = (const float*)d_in[4];
  const float* b_qkv = (const float*)d_in[5];
  const float* w_out = (const float*)d_in[6];
  const float* b_out = (const float*)d_in[7];
  const float* ln_g = (const float*)d_in[8];
  const float* ln_b = (const float*)d_in[9];
  const float* w1 = (const float*)d_in[10];
  const float* b1 = (const float*)d_in[11];
  const float* w2 = (const float*)d_in[12];
  const float* b2 = (const float*)d_in[13];
  float* out = (float*)d_out;
  (void)in_sizes; (void)n_in; (void)out_size; (void)d_ws; (void)ws_size;

  k_heads<<<4, 256, 0, stream>>>(cls, w_qkv, b_qkv);
  k_attn<<<1128, 256, 0, stream>>>(x, real_cols, real_rows, cls, w_qkv, b_qkv, w_out, w1, w2);
  k_token<<<256, 1024, 0, stream>>>(real_cols, real_rows, b_qkv, b_out, ln_g, ln_b, b1, b2, out);
}